// Round 4
// baseline (708.873 us; speedup 1.0000x reference)
//
#include <hip/hip_runtime.h>
#include <hip/hip_bf16.h>
#include <stdint.h>

#define LL 1024
#define BB 256
#define CC 96
#define HH 768
#define NW 9216   // CC*CC
#define NTOT 9408 // NW + 2*CC

typedef __attribute__((ext_vector_type(4))) float floatx4;
typedef __attribute__((ext_vector_type(2))) float floatx2;
typedef __attribute__((ext_vector_type(8))) short short8;

#define KAPPA 0x1p-16f
#define NEG_LOG_KAPPA 11.090354888959125f  // 16*ln2

__device__ __forceinline__ unsigned short f2bf(float f) {
  uint32_t u = __float_as_uint(f);
  return (unsigned short)((u + 0x7FFFu + ((u >> 16) & 1u)) >> 16);
}

// ---------------- fused bf16 MFMA GEMM: out = hidden @ [Wt;Ws;We]^T + bias ---
#define GA_LD 40  // ushort row stride: 80 B -> 2-way-max LDS conflicts (free)

__global__ __launch_bounds__(256) void gemm_mfma(
    const float* __restrict__ hidden, const float* __restrict__ Wt,
    const float* __restrict__ Ws, const float* __restrict__ We,
    const float* __restrict__ bt, const float* __restrict__ bs,
    const float* __restrict__ be, float* __restrict__ trans,
    float* __restrict__ tstart, float* __restrict__ tend) {
  __shared__ __align__(16) unsigned short As[128 * GA_LD];
  __shared__ __align__(16) unsigned short Bs[128 * GA_LD];
  const int t = threadIdx.x;
  const int lane = t & 63, wid = t >> 6;
  const int wm = wid >> 1, wn = wid & 1;
  const int l15 = lane & 15, qd = lane >> 4;
  const int m0 = blockIdx.y * 128, n0 = blockIdx.x * 128;
  const int srow = t >> 1, shalf = t & 1;

  floatx4 acc[4][4];
#pragma unroll
  for (int i = 0; i < 4; ++i)
#pragma unroll
    for (int j = 0; j < 4; ++j) acc[i][j] = (floatx4){0.f, 0.f, 0.f, 0.f};

  const int r = n0 + srow;
  const float* bsrc = (r < NW)        ? Wt + (size_t)r * HH
                      : (r < NW + CC) ? Ws + (size_t)(r - NW) * HH
                      : (r < NTOT)    ? We + (size_t)(r - NW - CC) * HH
                                      : nullptr;
  const float* asrc = hidden + (size_t)(m0 + srow) * HH;
  const int sidx = srow * GA_LD + shalf * 16;

  for (int k0 = 0; k0 < HH; k0 += 32) {
    __syncthreads();
    {  // stage A (fp32 -> bf16)
      const float4* s4 = (const float4*)(asrc + k0 + shalf * 16);
      uint32_t w[8];
#pragma unroll
      for (int u = 0; u < 4; ++u) {
        float4 v = s4[u];
        w[2 * u] = (uint32_t)f2bf(v.x) | ((uint32_t)f2bf(v.y) << 16);
        w[2 * u + 1] = (uint32_t)f2bf(v.z) | ((uint32_t)f2bf(v.w) << 16);
      }
      *(uint4*)&As[sidx] = make_uint4(w[0], w[1], w[2], w[3]);
      *(uint4*)&As[sidx + 8] = make_uint4(w[4], w[5], w[6], w[7]);
    }
    {  // stage B (fused row source)
      uint32_t w[8];
      if (bsrc) {
        const float4* s4 = (const float4*)(bsrc + k0 + shalf * 16);
#pragma unroll
        for (int u = 0; u < 4; ++u) {
          float4 v = s4[u];
          w[2 * u] = (uint32_t)f2bf(v.x) | ((uint32_t)f2bf(v.y) << 16);
          w[2 * u + 1] = (uint32_t)f2bf(v.z) | ((uint32_t)f2bf(v.w) << 16);
        }
      } else {
#pragma unroll
        for (int u = 0; u < 8; ++u) w[u] = 0u;
      }
      *(uint4*)&Bs[sidx] = make_uint4(w[0], w[1], w[2], w[3]);
      *(uint4*)&Bs[sidx + 8] = make_uint4(w[4], w[5], w[6], w[7]);
    }
    __syncthreads();
    short8 af[4], bf[4];
#pragma unroll
    for (int i = 0; i < 4; ++i)
      af[i] = *(const short8*)&As[(64 * wm + 16 * i + l15) * GA_LD + qd * 8];
#pragma unroll
    for (int j = 0; j < 4; ++j)
      bf[j] = *(const short8*)&Bs[(64 * wn + 16 * j + l15) * GA_LD + qd * 8];
#pragma unroll
    for (int i = 0; i < 4; ++i)
#pragma unroll
      for (int j = 0; j < 4; ++j)
        acc[i][j] = __builtin_amdgcn_mfma_f32_16x16x32_bf16(af[i], bf[j],
                                                            acc[i][j], 0, 0, 0);
  }

#pragma unroll
  for (int j = 0; j < 4; ++j) {
    int n = n0 + 64 * wn + 16 * j + l15;
    if (n >= NTOT) continue;
    float bv;
    float* dst;
    int ldo;
    if (n < NW) {
      bv = bt[n]; dst = trans + n; ldo = NW;
    } else if (n < NW + CC) {
      bv = bs[n - NW]; dst = tstart + (n - NW); ldo = CC;
    } else {
      bv = be[n - NW - CC]; dst = tend + (n - NW - CC); ldo = CC;
    }
#pragma unroll
    for (int i = 0; i < 4; ++i)
#pragma unroll
      for (int rr = 0; rr < 4; ++rr) {
        int m = m0 + 64 * wm + 16 * i + 4 * qd + rr;
        dst[(size_t)m * ldo] = acc[i][j][rr] + bv;
      }
  }
}

// ------- CRF scan v4: SINGLE WAVE, no barriers, wave-synchronous LDS --------
// lane = s*16+g. Lane owns outputs c in [6g,6g+6), input slice c' in [24s,24s+24).
// u stored skewed: addr(c) = c + 4*(c/24)  -> slice bases 0/28/56/84 (distinct banks)
#define CHUNK 16
#define USTRIDE 112

__device__ __forceinline__ float wredf(float v) {
#pragma unroll
  for (int m = 32; m >= 1; m >>= 1) v += __shfl_xor(v, m);
  return v;
}
__device__ __forceinline__ int wredi(int v) {
#pragma unroll
  for (int m = 32; m >= 1; m >>= 1) v += __shfl_xor(v, m);
  return v;
}

__global__ __launch_bounds__(64, 1) void crf_scan(
    const float* __restrict__ emit, const int* __restrict__ target,
    const void* __restrict__ mask, const float* __restrict__ trans,
    const float* __restrict__ tstart, const float* __restrict__ tend,
    float* __restrict__ out) {
  const int b = blockIdx.x;
  const int l = threadIdx.x;
  const int g = l & 15, s = l >> 4;

  __shared__ __align__(16) float u_lds[2 * USTRIDE];
  __shared__ __align__(16) float ebuf[2][CHUNK][CC];

  // ---- sequence length from mask (dtype sniffed at runtime) ----
  int cnt = 0;
  {
    unsigned w0 = *(const unsigned*)mask;
    if (w0 == 1u) {
      const int* m32 = (const int*)mask;
      for (int i = l; i < LL; i += 64) cnt += (m32[i * BB + b] != 0);
    } else if (w0 == 0x01010101u) {
      const unsigned char* m8 = (const unsigned char*)mask;
      for (int i = l; i < LL; i += 64) cnt += (m8[i * BB + b] != 0);
    } else {
      const float* mf = (const float*)mask;
      for (int i = l; i < LL; i += 64) cnt += (mf[i * BB + b] != 0.f);
    }
  }
  const int len = wredi(cnt);

  // ---- T = exp(trans): lane holds T[c'][c] for its slice x 6 outputs ----
  const float* tb = trans + (size_t)b * (CC * CC);
  floatx2 T0[24], T1[24], T2[24];
#pragma unroll
  for (int j = 0; j < 24; ++j) {
    const float* row = tb + (24 * s + j) * CC + 6 * g;
    T0[j] = (floatx2){__expf(row[0]), __expf(row[1])};
    T1[j] = (floatx2){__expf(row[2]), __expf(row[3])};
    T2[j] = (floatx2){__expf(row[4]), __expf(row[5])};
  }

  // ---- emit chunk pipeline: 64 lanes stage 16x96 floats per chunk ----
  int rowA[6], c4A[6], idx0[6];
#pragma unroll
  for (int u = 0; u < 6; ++u) {
    int v = l + 64 * u;
    rowA[u] = v / 24;
    c4A[u] = v - 24 * rowA[u];
    idx0[u] = (rowA[u] * BB + b) * 24 + c4A[u];
  }
  const float4* e4 = (const float4*)emit;
  float4 rr[6];
  // chunk 0 -> LDS directly
#pragma unroll
  for (int u = 0; u < 6; ++u) {
    float4 v = e4[idx0[u]];
    floatx4 o = {__expf(v.x) * KAPPA, __expf(v.y) * KAPPA,
                 __expf(v.z) * KAPPA, __expf(v.w) * KAPPA};
    *(floatx4*)&ebuf[0][rowA[u]][c4A[u] * 4] = o;
  }
  // chunk 1 -> regs
#pragma unroll
  for (int u = 0; u < 6; ++u) rr[u] = e4[idx0[u] + CHUNK * (BB * 24)];

  // ---- init: u0 = exp(a0 - a0[0]), L = a0[0] ----
  float a00 = emit[(size_t)b * CC] + tstart[b * CC];
  float L = a00;
  {
    int c = l;
    float v = emit[(size_t)b * CC + c] + tstart[b * CC + c];
    u_lds[c + 4 * (c / 24)] = __expf(v - a00);
    if (l < 32) {
      int c2 = l + 64;
      float v2 = emit[(size_t)b * CC + c2] + tstart[b * CC + c2];
      u_lds[c2 + 4 * (c2 / 24)] = __expf(v2 - a00);
    }
  }
  asm volatile("" ::: "memory");  // order init writes before loop reads (DS in-order in-wave)

  // ---- main recurrence: zero barriers ----
#pragma unroll 4
  for (int i = 1; i < len; ++i) {
    if ((i & (CHUNK - 1)) == 0) {  // stage next chunk
      int ch = i >> 4;
      int es = ch & 1;
#pragma unroll
      for (int u = 0; u < 6; ++u) {
        float4 v = rr[u];
        floatx4 o = {__expf(v.x) * KAPPA, __expf(v.y) * KAPPA,
                     __expf(v.z) * KAPPA, __expf(v.w) * KAPPA};
        *(floatx4*)&ebuf[es][rowA[u]][c4A[u] * 4] = o;
      }
      int nb = (ch + 1) * CHUNK;
      if (nb < LL) {
#pragma unroll
        for (int u = 0; u < 6; ++u) rr[u] = e4[idx0[u] + nb * (BB * 24)];
      }
      asm volatile("" ::: "memory");
    }
    const int slot_r = ((i + 1) & 1) * USTRIDE;
    float invP = 1.0f, piv = 1.0f;
    if ((i & 3) == 0) {
      piv = u_lds[slot_r];  // stale pivot (u_prev[0]); uniform address
      invP = 1.0f / piv;
    }
    const floatx4* up = (const floatx4*)&u_lds[slot_r + 28 * s];
    floatx2 a0e = {0.f, 0.f}, a0o = {0.f, 0.f};
    floatx2 a1e = {0.f, 0.f}, a1o = {0.f, 0.f};
    floatx2 a2e = {0.f, 0.f}, a2o = {0.f, 0.f};
#pragma unroll
    for (int j4 = 0; j4 < 6; ++j4) {
      floatx4 U = up[j4];
      int j = 4 * j4;
      a0e += T0[j] * U.x; a0o += T0[j + 1] * U.y;
      a0e += T0[j + 2] * U.z; a0o += T0[j + 3] * U.w;
      a1e += T1[j] * U.x; a1o += T1[j + 1] * U.y;
      a1e += T1[j + 2] * U.z; a1o += T1[j + 3] * U.w;
      a2e += T2[j] * U.x; a2o += T2[j + 1] * U.y;
      a2e += T2[j + 2] * U.z; a2o += T2[j + 3] * U.w;
    }
    floatx2 a0 = a0e + a0o, a1 = a1e + a1o, a2 = a2e + a2o;
    a0.x += __shfl_xor(a0.x, 16); a0.y += __shfl_xor(a0.y, 16);
    a1.x += __shfl_xor(a1.x, 16); a1.y += __shfl_xor(a1.y, 16);
    a2.x += __shfl_xor(a2.x, 16); a2.y += __shfl_xor(a2.y, 16);
    a0.x += __shfl_xor(a0.x, 32); a0.y += __shfl_xor(a0.y, 32);
    a1.x += __shfl_xor(a1.x, 32); a1.y += __shfl_xor(a1.y, 32);
    a2.x += __shfl_xor(a2.x, 32); a2.y += __shfl_xor(a2.y, 32);
    if (s == 0) {
      const float* eb = &ebuf[(i >> 4) & 1][i & (CHUNK - 1)][6 * g];
      floatx2 E0 = *(const floatx2*)(eb);
      floatx2 E1 = *(const floatx2*)(eb + 2);
      floatx2 E2 = *(const floatx2*)(eb + 4);
      float* w = &u_lds[(i & 1) * USTRIDE + 6 * g + 4 * (g >> 2)];
      *(floatx2*)(w) = a0 * E0 * invP;
      *(floatx2*)(w + 2) = a1 * E1 * invP;
      *(floatx2*)(w + 4) = a2 * E2 * invP;
    }
    if ((i & 3) == 0) L += __logf(piv);  // uniform, off-chain
    asm volatile("" ::: "memory");  // order writes before next iter's reads
  }

  // ---- log Z (wave reduction) ----
  const int fs = ((len - 1) & 1) * USTRIDE;
  float zp;
  {
    int c = l;
    zp = u_lds[fs + c + 4 * (c / 24)] * __expf(tend[b * CC + c]);
    if (l < 32) {
      int c2 = l + 64;
      zp += u_lds[fs + c2 + 4 * (c2 / 24)] * __expf(tend[b * CC + c2]);
    }
  }
  float zsum = wredf(zp);
  float logz = L + (float)(len - 1) * NEG_LOG_KAPPA + __logf(zsum);

  // ---- gold-path score ----
  float sc = 0.f;
  for (int i = l; i < len; i += 64) {
    int tg = target[i * BB + b];
    sc += emit[((size_t)i * BB + b) * CC + tg];
    if (i >= 1) {
      int tp = target[(i - 1) * BB + b];
      sc += tb[tp * CC + tg];
    }
  }
  float score = wredf(sc);
  if (l == 0) {
    int tg0 = target[b];
    int tgl = target[(len - 1) * BB + b];
    score += tstart[b * CC + tg0] + tend[b * CC + tgl];
    atomicAdd(out, (logz - score) * (1.0f / 256.0f));
  }
}

extern "C" void kernel_launch(void* const* d_in, const int* in_sizes, int n_in,
                              void* d_out, int out_size, void* d_ws, size_t ws_size,
                              hipStream_t stream) {
  const float* emit = (const float*)d_in[0];
  const float* hidden = (const float*)d_in[1];
  const int* target = (const int*)d_in[2];
  const void* mask = d_in[3];
  const float* Wt = (const float*)d_in[4];
  const float* bt = (const float*)d_in[5];
  const float* Ws = (const float*)d_in[6];
  const float* bs = (const float*)d_in[7];
  const float* We = (const float*)d_in[8];
  const float* be = (const float*)d_in[9];

  float* trans_ws = (float*)d_ws;                  // 256*9216
  float* ts_ws = trans_ws + (size_t)BB * CC * CC;  // 256*96
  float* te_ws = ts_ws + (size_t)BB * CC;          // 256*96

  hipMemsetAsync(d_out, 0, sizeof(float), stream);

  gemm_mfma<<<dim3((NTOT + 127) / 128, 2), 256, 0, stream>>>(
      hidden, Wt, Ws, We, bt, bs, be, trans_ws, ts_ws, te_ws);

  crf_scan<<<BB, 64, 0, stream>>>(emit, target, mask, trans_ws, ts_ws, te_ws,
                                  (float*)d_out);
}

// Round 5
// 640.213 us; speedup vs baseline: 1.1072x; 1.1072x over previous
//
#include <hip/hip_runtime.h>
#include <hip/hip_bf16.h>
#include <stdint.h>

#define LL 1024
#define BB 256
#define CC 96
#define HH 768
#define NW 9216   // CC*CC
#define NTOT 9408 // NW + 2*CC

typedef __attribute__((ext_vector_type(4))) float floatx4;
typedef __attribute__((ext_vector_type(2))) float floatx2;
typedef __attribute__((ext_vector_type(8))) short short8;

#define KAPPA 0x1p-16f
#define NEG_LOG_KAPPA 11.090354888959125f  // 16*ln2

__device__ __forceinline__ unsigned short f2bf(float f) {
  uint32_t u = __float_as_uint(f);
  return (unsigned short)((u + 0x7FFFu + ((u >> 16) & 1u)) >> 16);
}

// ---------------- fused bf16 MFMA GEMM: out = hidden @ [Wt;Ws;We]^T + bias ---
#define GA_LD 40  // ushort row stride: 80 B -> 2-way-max LDS conflicts (free)

__global__ __launch_bounds__(256) void gemm_mfma(
    const float* __restrict__ hidden, const float* __restrict__ Wt,
    const float* __restrict__ Ws, const float* __restrict__ We,
    const float* __restrict__ bt, const float* __restrict__ bs,
    const float* __restrict__ be, float* __restrict__ trans,
    float* __restrict__ tstart, float* __restrict__ tend) {
  __shared__ __align__(16) unsigned short As[128 * GA_LD];
  __shared__ __align__(16) unsigned short Bs[128 * GA_LD];
  const int t = threadIdx.x;
  const int lane = t & 63, wid = t >> 6;
  const int wm = wid >> 1, wn = wid & 1;
  const int l15 = lane & 15, qd = lane >> 4;
  const int m0 = blockIdx.y * 128, n0 = blockIdx.x * 128;
  const int srow = t >> 1, shalf = t & 1;

  floatx4 acc[4][4];
#pragma unroll
  for (int i = 0; i < 4; ++i)
#pragma unroll
    for (int j = 0; j < 4; ++j) acc[i][j] = (floatx4){0.f, 0.f, 0.f, 0.f};

  const int r = n0 + srow;
  const float* bsrc = (r < NW)        ? Wt + (size_t)r * HH
                      : (r < NW + CC) ? Ws + (size_t)(r - NW) * HH
                      : (r < NTOT)    ? We + (size_t)(r - NW - CC) * HH
                                      : nullptr;
  const float* asrc = hidden + (size_t)(m0 + srow) * HH;
  const int sidx = srow * GA_LD + shalf * 16;

  for (int k0 = 0; k0 < HH; k0 += 32) {
    __syncthreads();
    {  // stage A (fp32 -> bf16)
      const float4* s4 = (const float4*)(asrc + k0 + shalf * 16);
      uint32_t w[8];
#pragma unroll
      for (int u = 0; u < 4; ++u) {
        float4 v = s4[u];
        w[2 * u] = (uint32_t)f2bf(v.x) | ((uint32_t)f2bf(v.y) << 16);
        w[2 * u + 1] = (uint32_t)f2bf(v.z) | ((uint32_t)f2bf(v.w) << 16);
      }
      *(uint4*)&As[sidx] = make_uint4(w[0], w[1], w[2], w[3]);
      *(uint4*)&As[sidx + 8] = make_uint4(w[4], w[5], w[6], w[7]);
    }
    {  // stage B (fused row source)
      uint32_t w[8];
      if (bsrc) {
        const float4* s4 = (const float4*)(bsrc + k0 + shalf * 16);
#pragma unroll
        for (int u = 0; u < 4; ++u) {
          float4 v = s4[u];
          w[2 * u] = (uint32_t)f2bf(v.x) | ((uint32_t)f2bf(v.y) << 16);
          w[2 * u + 1] = (uint32_t)f2bf(v.z) | ((uint32_t)f2bf(v.w) << 16);
        }
      } else {
#pragma unroll
        for (int u = 0; u < 8; ++u) w[u] = 0u;
      }
      *(uint4*)&Bs[sidx] = make_uint4(w[0], w[1], w[2], w[3]);
      *(uint4*)&Bs[sidx + 8] = make_uint4(w[4], w[5], w[6], w[7]);
    }
    __syncthreads();
    short8 af[4], bf[4];
#pragma unroll
    for (int i = 0; i < 4; ++i)
      af[i] = *(const short8*)&As[(64 * wm + 16 * i + l15) * GA_LD + qd * 8];
#pragma unroll
    for (int j = 0; j < 4; ++j)
      bf[j] = *(const short8*)&Bs[(64 * wn + 16 * j + l15) * GA_LD + qd * 8];
#pragma unroll
    for (int i = 0; i < 4; ++i)
#pragma unroll
      for (int j = 0; j < 4; ++j)
        acc[i][j] = __builtin_amdgcn_mfma_f32_16x16x32_bf16(af[i], bf[j],
                                                            acc[i][j], 0, 0, 0);
  }

#pragma unroll
  for (int j = 0; j < 4; ++j) {
    int n = n0 + 64 * wn + 16 * j + l15;
    if (n >= NTOT) continue;
    float bv;
    float* dst;
    int ldo;
    if (n < NW) {
      bv = bt[n]; dst = trans + n; ldo = NW;
    } else if (n < NW + CC) {
      bv = bs[n - NW]; dst = tstart + (n - NW); ldo = CC;
    } else {
      bv = be[n - NW - CC]; dst = tend + (n - NW - CC); ldo = CC;
    }
#pragma unroll
    for (int i = 0; i < 4; ++i)
#pragma unroll
      for (int rr = 0; rr < 4; ++rr) {
        int m = m0 + 64 * wm + 16 * i + 4 * qd + rr;
        dst[(size_t)m * ldo] = acc[i][j][rr] + bv;
      }
  }
}

// ------- CRF scan v5: single wave, DPP-only cross-lane, single u buffer -----
// lane = 2*pr + s. Lane owns outputs 3pr..3pr+2, input half 48s..48s+47.
// Combine: one __shfl_xor(x,1) per output (quad-perm DPP, no 32-lane issues).
#define CHUNK 8
#define EROW 100

__device__ __forceinline__ float wredf(float v) {
#pragma unroll
  for (int m = 32; m >= 1; m >>= 1) v += __shfl_xor(v, m);
  return v;
}
__device__ __forceinline__ int wredi(int v) {
#pragma unroll
  for (int m = 32; m >= 1; m >>= 1) v += __shfl_xor(v, m);
  return v;
}
__device__ __forceinline__ float bcast0(float x) {
  return __uint_as_float(__builtin_amdgcn_readfirstlane(__float_as_uint(x)));
}

__global__ __launch_bounds__(64, 1) void crf_scan(
    const float* __restrict__ emit, const int* __restrict__ target,
    const void* __restrict__ mask, const float* __restrict__ trans,
    const float* __restrict__ tstart, const float* __restrict__ tend,
    float* __restrict__ out) {
  const int b = blockIdx.x;
  const int l = threadIdx.x;
  const int pr = l >> 1, s = l & 1;

  __shared__ __align__(16) float u_lds[CC];
  __shared__ __align__(16) float ebuf[2][CHUNK][EROW];

  // ---- sequence length from mask (dtype sniffed at runtime) ----
  int cnt = 0;
  {
    unsigned w0 = *(const unsigned*)mask;
    if (w0 == 1u) {
      const int* m32 = (const int*)mask;
      for (int i = l; i < LL; i += 64) cnt += (m32[i * BB + b] != 0);
    } else if (w0 == 0x01010101u) {
      const unsigned char* m8 = (const unsigned char*)mask;
      for (int i = l; i < LL; i += 64) cnt += (m8[i * BB + b] != 0);
    } else {
      const float* mf = (const float*)mask;
      for (int i = l; i < LL; i += 64) cnt += (mf[i * BB + b] != 0.f);
    }
  }
  const int len = wredi(cnt);

  // ---- T2[o][j] = (expT[48s+2j][3pr+o], expT[48s+2j+1][3pr+o]) ----
  const float* tb = trans + (size_t)b * (CC * CC);
  floatx2 T2[3][24];
#pragma unroll
  for (int j = 0; j < 24; ++j) {
    const float* r0 = tb + (48 * s + 2 * j) * CC + 3 * pr;
    const float* r1 = r0 + CC;
#pragma unroll
    for (int o = 0; o < 3; ++o)
      T2[o][j] = (floatx2){__expf(r0[o]), __expf(r1[o])};
  }

  // ---- emit chunk pipeline: 64 lanes stage 8x96 floats per chunk ----
  int idx0[3], rowA[3], c4A[3];
#pragma unroll
  for (int u = 0; u < 3; ++u) {
    int v = l + 64 * u;
    rowA[u] = v / 24;
    c4A[u] = v - 24 * rowA[u];
    idx0[u] = (rowA[u] * BB + b) * 24 + c4A[u];
  }
  const float4* e4 = (const float4*)emit;
  float4 rr[3];
#pragma unroll
  for (int u = 0; u < 3; ++u) {  // chunk 0 -> LDS
    float4 v = e4[idx0[u]];
    floatx4 o = {__expf(v.x) * KAPPA, __expf(v.y) * KAPPA,
                 __expf(v.z) * KAPPA, __expf(v.w) * KAPPA};
    *(floatx4*)&ebuf[0][rowA[u]][c4A[u] * 4] = o;
  }
#pragma unroll
  for (int u = 0; u < 3; ++u) rr[u] = e4[idx0[u] + CHUNK * (BB * 24)];  // chunk 1

  // ---- init: u0 = exp(a0 - a0[0]), L = a0[0] ----
  float a00 = emit[(size_t)b * CC] + tstart[b * CC];
  float L = a00;
  {
    float v = emit[(size_t)b * CC + l] + tstart[b * CC + l];
    u_lds[l] = __expf(v - a00);
    if (l < 32) {
      int c2 = l + 64;
      float v2 = emit[(size_t)b * CC + c2] + tstart[b * CC + c2];
      u_lds[c2] = __expf(v2 - a00);
    }
  }
  asm volatile("" ::: "memory");  // in-wave DS in-order: no barrier needed

  float pv = 1.0f;  // carries u_prev[0] (set each iter via readfirstlane)

  // ---- main recurrence: zero barriers, DPP-only combine ----
  for (int i = 1; i < len; ++i) {
    if ((i & (CHUNK - 1)) == 0) {  // stage next chunk
      int ch = i >> 3;
      int es = ch & 1;
#pragma unroll
      for (int u = 0; u < 3; ++u) {
        float4 v = rr[u];
        floatx4 o = {__expf(v.x) * KAPPA, __expf(v.y) * KAPPA,
                     __expf(v.z) * KAPPA, __expf(v.w) * KAPPA};
        *(floatx4*)&ebuf[es][rowA[u]][c4A[u] * 4] = o;
      }
      int nb = (ch + 1) * CHUNK;
      if (nb < LL) {
#pragma unroll
        for (int u = 0; u < 3; ++u) rr[u] = e4[idx0[u] + nb * (BB * 24)];
      }
      asm volatile("" ::: "memory");
    }
    float invP = 1.0f;
    if ((i & 3) == 0) {  // renorm: pivot from register, off-chain
      invP = 1.0f / pv;
      L += __logf(pv);
    }
    // E values (independent of u -> issue early): even=(E[3pr],E[3pr+1]) odd=(E[3pr+2],·)
    floatx2 Ep = *(const floatx2*)&ebuf[(i >> 3) & 1][i & (CHUNK - 1)][3 * pr + 2 * s];
    // u half-slice: 12 broadcast b128 reads
    const floatx4* up = (const floatx4*)&u_lds[48 * s];
    floatx2 A0 = {0.f, 0.f}, B0 = {0.f, 0.f};
    floatx2 A1 = {0.f, 0.f}, B1 = {0.f, 0.f};
    floatx2 A2 = {0.f, 0.f}, B2 = {0.f, 0.f};
#pragma unroll
    for (int j4 = 0; j4 < 12; ++j4) {
      floatx4 U = up[j4];
      floatx2 lo = {U.x, U.y}, hi = {U.z, U.w};
      A0 += lo * T2[0][2 * j4]; B0 += hi * T2[0][2 * j4 + 1];
      A1 += lo * T2[1][2 * j4]; B1 += hi * T2[1][2 * j4 + 1];
      A2 += lo * T2[2][2 * j4]; B2 += hi * T2[2][2 * j4 + 1];
    }
    floatx2 S0 = A0 + B0, S1 = A1 + B1, S2 = A2 + B2;
    float a0 = S0.x + S0.y, a1 = S1.x + S1.y, a2 = S2.x + S2.y;
    a0 += __shfl_xor(a0, 1);  // quad-perm DPP: cheap, stays in half
    a1 += __shfl_xor(a1, 1);
    a2 += __shfl_xor(a2, 1);
    float nw0 = a0 * Ep.x * invP;  // on even lanes: u_new[3pr]; lane0: u_new[0]
    pv = bcast0(nw0);
    if (s == 0) {
      floatx2 wv = {nw0, a1 * Ep.y * invP};
      *(floatx2*)&u_lds[3 * pr] = wv;
    } else {
      u_lds[3 * pr + 2] = a2 * Ep.x * invP;
    }
    asm volatile("" ::: "memory");
  }

  // ---- log Z (wave reduction; slow shfl OK once) ----
  float zp;
  {
    zp = u_lds[l] * __expf(tend[b * CC + l]);
    if (l < 32) {
      int c2 = l + 64;
      zp += u_lds[c2] * __expf(tend[b * CC + c2]);
    }
  }
  float zsum = wredf(zp);
  float logz = L + (float)(len - 1) * NEG_LOG_KAPPA + __logf(zsum);

  // ---- gold-path score ----
  float sc = 0.f;
  for (int i = l; i < len; i += 64) {
    int tg = target[i * BB + b];
    sc += emit[((size_t)i * BB + b) * CC + tg];
    if (i >= 1) {
      int tp = target[(i - 1) * BB + b];
      sc += tb[tp * CC + tg];
    }
  }
  float score = wredf(sc);
  if (l == 0) {
    int tg0 = target[b];
    int tgl = target[(len - 1) * BB + b];
    score += tstart[b * CC + tg0] + tend[b * CC + tgl];
    atomicAdd(out, (logz - score) * (1.0f / 256.0f));
  }
}

extern "C" void kernel_launch(void* const* d_in, const int* in_sizes, int n_in,
                              void* d_out, int out_size, void* d_ws, size_t ws_size,
                              hipStream_t stream) {
  const float* emit = (const float*)d_in[0];
  const float* hidden = (const float*)d_in[1];
  const int* target = (const int*)d_in[2];
  const void* mask = d_in[3];
  const float* Wt = (const float*)d_in[4];
  const float* bt = (const float*)d_in[5];
  const float* Ws = (const float*)d_in[6];
  const float* bs = (const float*)d_in[7];
  const float* We = (const float*)d_in[8];
  const float* be = (const float*)d_in[9];

  float* trans_ws = (float*)d_ws;                  // 256*9216
  float* ts_ws = trans_ws + (size_t)BB * CC * CC;  // 256*96
  float* te_ws = ts_ws + (size_t)BB * CC;          // 256*96

  hipMemsetAsync(d_out, 0, sizeof(float), stream);

  gemm_mfma<<<dim3((NTOT + 127) / 128, 2), 256, 0, stream>>>(
      hidden, Wt, Ws, We, bt, bs, be, trans_ws, ts_ws, te_ws);

  crf_scan<<<BB, 64, 0, stream>>>(emit, target, mask, trans_ws, ts_ws, te_ws,
                                  (float*)d_out);
}